// Round 3
// baseline (7569.900 us; speedup 1.0000x reference)
//
#include <hip/hip_runtime.h>
#include <math.h>

typedef unsigned int u32;

#define N_NODES 100000
#define N_EDGES 1000000
#define NB      64
#define NODES_PER_G 1562   // N // B; graph 63 holds 1594
#define CH_PER_G 100       // ceil(1594/16)

__device__ __forceinline__ float sigmoidf_(float x){ return 1.f/(1.f+__expf(-x)); }
__device__ __forceinline__ float ftanh(float x){
  float e = __expf(-2.f*fabsf(x));
  float t = (1.f - e)/(1.f + e);
  return copysignf(t, x);
}

// load a 128-wide fp32 row (512B, 16B aligned) into 32 float4 regs
__device__ __forceinline__ void ldrowf(const float* p, float4* w){
  const float4* q = (const float4*)p;
#pragma unroll
  for(int i=0;i<32;i++) w[i] = q[i];
}
__device__ __forceinline__ float dotf128(const float4* w, const float* x){
  float a=0.f;
#pragma unroll
  for(int i=0;i<32;i++){
    float4 t = w[i];
    a = fmaf(t.x, x[4*i+0], a);
    a = fmaf(t.y, x[4*i+1], a);
    a = fmaf(t.z, x[4*i+2], a);
    a = fmaf(t.w, x[4*i+3], a);
  }
  return a;
}

// ---------------- per-graph precompute: s2s, s2m, w2(=dsup*mC), gmB_lin ----------
__global__ void k_sup(const float* __restrict__ s,
                      const float* A_w, const float* A_b,
                      const float* C_w, const float* C_b,
                      const float* mB_w, const float* mB_b, const float* mC_w,
                      const float* gmB_w, const float* gmB_b,
                      float* s2s, float* s2m_g, float* w2, float* gmB_lin){
  int b = blockIdx.x, h = threadIdx.x;
  __shared__ float sb[128], s2ml[128];
  sb[h] = s[b*128+h];
  __syncthreads();
  float4 w[32];
  ldrowf(A_w + h*128, w);
  s2s[b*128+h] = ftanh(dotf128(w, sb) + A_b[h]);
  ldrowf(C_w + h*128, w);
  float sm = ftanh(dotf128(w, sb) + C_b[h]);
  s2m_g[b*128+h] = sm; s2ml[h] = sm;
  for(int k=0;k<4;k++){
    ldrowf(mB_w + (size_t)(k*128+h)*128, w);
    float d = ftanh(dotf128(w, sb) + mB_b[k*128+h]);
    w2[b*512 + k*128 + h] = d * mC_w[k*128+h];
  }
  __syncthreads();
  ldrowf(gmB_w + h*128, w);
  gmB_lin[b*128+h] = dotf128(w, s2ml) + gmB_b[h];
}

// ------------- merged attention: logits (no-max exp, bounded) + numerator --------
__global__ __launch_bounds__(512) void k_att(const float* __restrict__ v, const float* __restrict__ w2,
                      const float* mA_w, const float* mA_b, const float* mC_b,
                      const float* mD_w, const float* mD_b,
                      float* __restrict__ asum, float* __restrict__ m2s_num){
  int g = blockIdx.x / CH_PER_G, chunk = blockIdx.x % CH_PER_G;
  int start = g*NODES_PER_G, end = (g==NB-1)? N_NODES : start+NODES_PER_G;
  int node0 = start + chunk*16;
  int cnt = end - node0; if(cnt<=0) return; if(cnt>16) cnt=16;
  int t = threadIdx.x; int k = t>>7; int wv = t>>6;   // head, wave id
  __shared__ float vl[16][128];
  __shared__ float red[16][8];
  __shared__ float ael[16][4];
  for(int i=t;i<16*128;i+=512){
    int n=i>>7, c=i&127;
    vl[n][c] = (n<cnt) ? v[(size_t)(node0+n)*128+c] : 0.f;
  }
  float4 w[32]; ldrowf(mA_w + (size_t)t*128, w);
  float biasA = mA_b[t];
  float wc = w2[g*512+t];
  __syncthreads();
  for(int n=0;n<16;n++){
    float d = ftanh(dotf128(w, vl[n]) + biasA) * wc;
    for(int o=32;o>0;o>>=1) d += __shfl_down(d, o);
    if((t&63)==0) red[n][wv] = d;
  }
  __syncthreads();
  if(t<64){
    int n=t>>2, kk=t&3;
    float ae=0.f;
    if(n<cnt){
      // |logit| bounded by sum|mC_w|+|mC_b| (~6): exp safe without max-subtraction
      ae = __expf(red[n][2*kk] + red[n][2*kk+1] + mC_b[kk]);
      atomicAdd(&asum[g*4+kk], ae);
    }
    ael[n][kk]=ae;
  }
  ldrowf(mD_w + (size_t)t*128, w);
  float biasD = mD_b[t];
  __syncthreads();
  float acc=0.f;
  for(int n=0;n<16;n++){
    float d = dotf128(w, vl[n]) + biasD;
    acc = fmaf(d, ael[n][k], acc);
  }
  atomicAdd(&m2s_num[(size_t)g*512 + t], acc);
}

// ---------------- edge message + scatter-add into nbuf (dst-range filtered) -------
__global__ void k_edge(const float* __restrict__ v, const float* __restrict__ e,
                       const int* __restrict__ src, const int* __restrict__ dst,
                       const float* K_w, const float* K_b,
                       float* __restrict__ nbuf, int lo, int hi){
  int h = threadIdx.x;             // 0..127
  int e0 = blockIdx.x * 16;
  __shared__ float el[16][16];
  __shared__ int sl[16], dl[16];
  for(int i=h;i<256;i+=128){ int ee=i>>4, c=i&15; el[ee][c]=e[(size_t)(e0+ee)*16+c]; }
  if(h<16){ sl[h]=src[e0+h]; dl[h]=dst[e0+h]; }
  float4 kw[4];
  { const float4* q=(const float4*)(K_w + h*16);
    kw[0]=q[0]; kw[1]=q[1]; kw[2]=q[2]; kw[3]=q[3]; }
  float kb = K_b[h];
  __syncthreads();
  for(int j=0;j<16;j++){
    int dj = dl[j];
    if(dj < lo || dj >= hi) continue;
    int sj = sl[j]; if((u32)sj >= (u32)N_NODES) sj = 0;
    float kv=kb;
#pragma unroll
    for(int i=0;i<4;i++){
      float4 t = kw[i];
      kv = fmaf(t.x, el[j][4*i+0], kv);
      kv = fmaf(t.y, el[j][4*i+1], kv);
      kv = fmaf(t.z, el[j][4*i+2], kv);
      kv = fmaf(t.w, el[j][4*i+3], kv);
    }
    float vs = v[(size_t)sj*128+h];
    float val = kv*vs; val = (val>0.f)? val : 0.1f*val;
    atomicAdd(&nbuf[(size_t)(dj-lo)*128+h], val);
  }
}

// ---------------- m2m = leaky(E_w @ [sve;v] + E_b), in-place over nbuf ------------
__global__ void k_m2m(const float* __restrict__ v, const float* E_w, const float* E_b,
                      float* __restrict__ nbuf, int lo){
  int t=threadIdx.x; int h=t&127, half=t>>7;
  int nl0 = blockIdx.x*8;
  __shared__ float xl[8][256];
  __shared__ float ps[8][128];
  for(int i=t;i<8*128;i+=256){ int n=i>>7,c=i&127; xl[n][c]=nbuf[(size_t)(nl0+n)*128+c]; }
  for(int i=t;i<8*128;i+=256){ int n=i>>7,c=i&127; xl[n][128+c]=v[(size_t)(lo+nl0+n)*128+c]; }
  float4 w[32]; ldrowf(E_w + (size_t)h*256 + half*128, w);
  __syncthreads();
  float acc[8];
#pragma unroll
  for(int n=0;n<8;n++) acc[n] = dotf128(w, &xl[n][half*128]);
  if(half==1){
#pragma unroll
    for(int n=0;n<8;n++) ps[n][h]=acc[n];
  }
  __syncthreads();
  if(half==0){
    float eb = E_b[h];
#pragma unroll
    for(int n=0;n<8;n++){
      float m = acc[n]+ps[n][h]+eb;
      m = (m>0.f)?m:0.1f*m;
      nbuf[(size_t)(nl0+n)*128+h] = m;
    }
  }
}

// ---------------- adaptive gate: h = z*s2m + (1-z)*m2m, in-place over nbuf --------
__global__ void k_gate(const int* __restrict__ graph_id,
                       const float* __restrict__ s2m_g, const float* __restrict__ gmB_lin,
                       const float* gmA_w, const float* gmA_b,
                       float* __restrict__ nbuf, int lo){
  int t=threadIdx.x; int h=t&127, tg=t>>7;
  int nl0=blockIdx.x*8;
  __shared__ float xl[8][128];
  for(int i=t;i<1024;i+=256){int n=i>>7,c=i&127; xl[n][c]=nbuf[(size_t)(nl0+n)*128+c];}
  float4 w[32]; ldrowf(gmA_w + (size_t)h*128, w);
  float ab = gmA_b[h];
  __syncthreads();
  for(int nn=0;nn<4;nn++){
    int n = tg*4+nn;
    int node = lo+nl0+n;
    int g = graph_id[node] & 63;
    float z = sigmoidf_(dotf128(w, xl[n]) + ab + gmB_lin[g*128+h]);
    float hg = z*s2m_g[g*128+h] + (1.f-z)*xl[n][h];
    nbuf[(size_t)(nl0+n)*128+h] = hg;
  }
}

// ---------------- node GRU: update_v -----------------------------------------------
__global__ void k_gru(const float* __restrict__ v,
                      const float* wih, const float* bih,
                      const float* whh, const float* bhh,
                      const float* __restrict__ nbuf,
                      float* __restrict__ out, int lo){
  int t=threadIdx.x;
  int nl0=blockIdx.x*8;
  __shared__ float xl[8][256];     // [:,0:128]=v  [:,128:256]=hgate
  __shared__ float accl[8][768];   // [0,384)=gi, [384,768)=gh
  for(int i=t;i<1024;i+=256){
    int n=i>>7,c=i&127;
    xl[n][c]     = v[(size_t)(lo+nl0+n)*128+c];
    xl[n][128+c] = nbuf[(size_t)(nl0+n)*128+c];
  }
  __syncthreads();
  for(int ri=0;ri<3;ri++){
    int r = t + ri*256;
    const float* wrow; float bias; int xoff;
    if(r<384){ wrow = wih + (size_t)r*128;       bias = bih[r];     xoff=0;   }
    else     { wrow = whh + (size_t)(r-384)*128; bias = bhh[r-384]; xoff=128; }
    float4 w[32]; ldrowf(wrow, w);
    for(int n=0;n<8;n++) accl[n][r] = dotf128(w, &xl[n][xoff]) + bias;
  }
  __syncthreads();
  for(int i=t;i<1024;i+=256){
    int n=i>>7, h=i&127;
    float ir=accl[n][h], iz=accl[n][h+128], inn=accl[n][h+256];
    float hr=accl[n][384+h], hz=accl[n][512+h], hn=accl[n][640+h];
    float r = sigmoidf_(ir+hr), z = sigmoidf_(iz+hz);
    float nnv = ftanh(inn + r*hn);
    float hg = xl[n][128+h];
    out[(size_t)(lo+nl0+n)*128+h] = (1.f-z)*nnv + z*hg;
  }
}

// ---------------- supernode finish: m2s, gate, GRU -> update_s ---------------------
__global__ void k_sup2(const float* __restrict__ s,
                       const float* __restrict__ m2s_num, const float* __restrict__ asum,
                       const float* __restrict__ s2s,
                       const float* B_w, const float* B_b,
                       const float* gsA_w, const float* gsA_b,
                       const float* gsB_w, const float* gsB_b,
                       const float* wih, const float* bih, const float* whh, const float* bhh,
                       float* __restrict__ out){
  int b=blockIdx.x, h=threadIdx.x;
  __shared__ float m2si[512], m2sl[128], s2sl[128], sl[128], hgl[128];
  for(int j=0;j<4;j++){ int kh=h+j*128; m2si[kh] = m2s_num[b*512+kh] / asum[b*4 + (kh>>7)]; }
  s2sl[h]=s2s[b*128+h];
  sl[h]=s[b*128+h];
  __syncthreads();
  float acc = B_b[h];
  { const float4* q=(const float4*)(B_w + (size_t)h*512);
    for(int i=0;i<128;i++){
      float4 p=q[i]; int base=i*4;
      acc=fmaf(p.x,m2si[base+0],acc); acc=fmaf(p.y,m2si[base+1],acc);
      acc=fmaf(p.z,m2si[base+2],acc); acc=fmaf(p.w,m2si[base+3],acc);
    }
  }
  float m2sv = ftanh(acc);
  m2sl[h]=m2sv;
  __syncthreads();
  float4 w[32];
  ldrowf(gsA_w+(size_t)h*128, w);
  float zacc = dotf128(w, s2sl) + gsA_b[h];
  ldrowf(gsB_w+(size_t)h*128, w);
  zacc += dotf128(w, m2sl) + gsB_b[h];
  float z = sigmoidf_(zacc);
  float hg = z*m2sl[h] + (1.f-z)*s2sl[h];
  hgl[h]=hg;
  __syncthreads();
  float gi[3], gh[3];
  for(int j=0;j<3;j++){
    ldrowf(wih+(size_t)(h+j*128)*128, w);
    gi[j]=dotf128(w, sl)+bih[h+j*128];
    ldrowf(whh+(size_t)(h+j*128)*128, w);
    gh[j]=dotf128(w, hgl)+bhh[h+j*128];
  }
  float r=sigmoidf_(gi[0]+gh[0]), z2=sigmoidf_(gi[1]+gh[1]);
  float nn=ftanh(gi[2]+r*gh[2]);
  out[(size_t)N_NODES*128 + b*128 + h] = (1.f-z2)*nn + z2*hg;
}

extern "C" void kernel_launch(void* const* d_in, const int* in_sizes, int n_in,
                              void* d_out, int out_size, void* d_ws, size_t ws_size,
                              hipStream_t stream){
  const float* v   = (const float*)d_in[0];
  const float* e   = (const float*)d_in[1];
  const float* s   = (const float*)d_in[2];
  const int* src  = (const int*)d_in[3];
  const int* dst  = (const int*)d_in[4];
  const int* graph_id = (const int*)d_in[5];
  const float* A_w=(const float*)d_in[6];  const float* A_b=(const float*)d_in[7];
  const float* B_w=(const float*)d_in[8];  const float* B_b=(const float*)d_in[9];
  const float* C_w=(const float*)d_in[10]; const float* C_b=(const float*)d_in[11];
  const float* E_w=(const float*)d_in[12]; const float* E_b=(const float*)d_in[13];
  const float* K_w=(const float*)d_in[14]; const float* K_b=(const float*)d_in[15];
  const float* mA_w=(const float*)d_in[16]; const float* mA_b=(const float*)d_in[17];
  const float* mB_w=(const float*)d_in[18]; const float* mB_b=(const float*)d_in[19];
  const float* mC_w=(const float*)d_in[20]; const float* mC_b=(const float*)d_in[21];
  const float* mD_w=(const float*)d_in[22]; const float* mD_b=(const float*)d_in[23];
  const float* gmA_w=(const float*)d_in[24]; const float* gmA_b=(const float*)d_in[25];
  const float* gmB_w=(const float*)d_in[26]; const float* gmB_b=(const float*)d_in[27];
  const float* gm_wih=(const float*)d_in[28]; const float* gm_bih=(const float*)d_in[29];
  const float* gm_whh=(const float*)d_in[30]; const float* gm_bhh=(const float*)d_in[31];
  const float* gsA_w=(const float*)d_in[32]; const float* gsA_b=(const float*)d_in[33];
  const float* gsB_w=(const float*)d_in[34]; const float* gsB_b=(const float*)d_in[35];
  const float* gs_wih=(const float*)d_in[36]; const float* gs_bih=(const float*)d_in[37];
  const float* gs_whh=(const float*)d_in[38]; const float* gs_bhh=(const float*)d_in[39];

  float* ws = (float*)d_ws;
  // small buffers first (always fit)
  float* asum    = ws;                  // 256
  float* m2s_num = asum + 256;          // 64*512 = 32768
  float* s2s     = m2s_num + 32768;     // 8192
  float* s2m_g   = s2s + 8192;          // 8192
  float* gmB_lin = s2m_g + 8192;        // 8192
  float* w2      = gmB_lin + 8192;      // 32768
  float* nbuf    = w2 + 32768;          // chunked node buffer
  const size_t small_f = 256 + 32768 + 8192*3 + 32768;   // 90368 floats

  // adaptive node-chunk size from actual ws_size
  size_t ws_f = ws_size / 4;
  long avail = (ws_f > small_f) ? (long)(ws_f - small_f) : 0;
  long M = (avail / 128) & ~7L;
  if(M > N_NODES) M = N_NODES;
  if(M < 8) M = 8;

  hipMemsetAsync(asum, 0, (256 + 32768) * sizeof(float), stream);

  k_sup <<<NB, 128, 0, stream>>>(s, A_w,A_b, C_w,C_b, mB_w,mB_b,mC_w, gmB_w,gmB_b,
                                 s2s, s2m_g, w2, gmB_lin);
  k_att <<<NB*CH_PER_G, 512, 0, stream>>>(v, w2, mA_w, mA_b, mC_b, mD_w, mD_b,
                                          asum, m2s_num);
  k_sup2<<<NB, 128, 0, stream>>>(s, m2s_num, asum, s2s, B_w,B_b,
                                 gsA_w,gsA_b, gsB_w,gsB_b,
                                 gs_wih,gs_bih, gs_whh,gs_bhh, (float*)d_out);

  for(long lo = 0; lo < N_NODES; lo += M){
    long cnt = N_NODES - lo; if(cnt > M) cnt = M;       // multiple of 8
    int ilo = (int)lo, icnt = (int)cnt;
    hipMemsetAsync(nbuf, 0, (size_t)icnt*128*sizeof(float), stream);
    k_edge<<<N_EDGES/16, 128, 0, stream>>>(v, e, src, dst, K_w, K_b, nbuf, ilo, ilo+icnt);
    k_m2m <<<icnt/8, 256, 0, stream>>>(v, E_w, E_b, nbuf, ilo);
    k_gate<<<icnt/8, 256, 0, stream>>>(graph_id, s2m_g, gmB_lin, gmA_w, gmA_b, nbuf, ilo);
    k_gru <<<icnt/8, 256, 0, stream>>>(v, gm_wih, gm_bih, gm_whh, gm_bhh, nbuf,
                                       (float*)d_out, ilo);
  }
}

// Round 4
// 2354.006 us; speedup vs baseline: 3.2158x; 3.2158x over previous
//
#include <hip/hip_runtime.h>
#include <math.h>

typedef unsigned int u32;

#define N_NODES 100000
#define N_EDGES 1000000
#define NB      64
#define NODES_PER_G 1562   // N // B; graph 63 holds 1594
#define CH_PER_G 100       // ceil(1594/16)

__device__ __forceinline__ float sigmoidf_(float x){ return 1.f/(1.f+__expf(-x)); }
__device__ __forceinline__ float ftanh(float x){
  float e = __expf(-2.f*fabsf(x));
  float t = (1.f - e)/(1.f + e);
  return copysignf(t, x);
}

// streaming 128-dot: weights from global (L2-hot), x from LDS; no big reg arrays
__device__ __forceinline__ float dots(const float* w, const float* x){
  const float4* w4 = (const float4*)w;
  float a = 0.f;
#pragma unroll 8
  for(int i=0;i<32;i++){
    float4 t = w4[i];
    a = fmaf(t.x, x[4*i+0], a);
    a = fmaf(t.y, x[4*i+1], a);
    a = fmaf(t.z, x[4*i+2], a);
    a = fmaf(t.w, x[4*i+3], a);
  }
  return a;
}

// ---------------- per-graph precompute: s2s, s2m, w2(=dsup*mC), gmB_lin ----------
__global__ __launch_bounds__(128,4) void k_sup(const float* __restrict__ s,
                      const float* A_w, const float* A_b,
                      const float* C_w, const float* C_b,
                      const float* mB_w, const float* mB_b, const float* mC_w,
                      const float* gmB_w, const float* gmB_b,
                      float* s2s, float* s2m_g, float* w2, float* gmB_lin){
  int b = blockIdx.x, h = threadIdx.x;
  __shared__ float sb[128], s2ml[128];
  sb[h] = s[b*128+h];
  __syncthreads();
  s2s[b*128+h] = ftanh(dots(A_w + h*128, sb) + A_b[h]);
  float sm = ftanh(dots(C_w + h*128, sb) + C_b[h]);
  s2m_g[b*128+h] = sm; s2ml[h] = sm;
  for(int k=0;k<4;k++){
    float d = ftanh(dots(mB_w + (size_t)(k*128+h)*128, sb) + mB_b[k*128+h]);
    w2[b*512 + k*128 + h] = d * mC_w[k*128+h];
  }
  __syncthreads();
  gmB_lin[b*128+h] = dots(gmB_w + h*128, s2ml) + gmB_b[h];
}

// ------------- merged attention: mA+mD fused kc loop, no-max exp (bounded) --------
__global__ __launch_bounds__(512,2) void k_att(const float* __restrict__ v, const float* __restrict__ w2,
                      const float* __restrict__ mA_w, const float* __restrict__ mA_b,
                      const float* __restrict__ mC_b,
                      const float* __restrict__ mD_w, const float* __restrict__ mD_b,
                      float* __restrict__ asum, float* __restrict__ m2s_num){
  int g = blockIdx.x / CH_PER_G, chunk = blockIdx.x % CH_PER_G;
  int start = g*NODES_PER_G, end = (g==NB-1)? N_NODES : start+NODES_PER_G;
  int node0 = start + chunk*16;
  int cnt = end - node0; if(cnt<=0) return; if(cnt>16) cnt=16;
  int t = threadIdx.x; int k = t>>7; int wv = t>>6;
  __shared__ float vl[16][128];
  __shared__ float red[16][8];
  __shared__ float ael[16][4];
  for(int i=t;i<16*32;i+=512){
    int n=i>>5, c=i&31;
    float4 val = (n<cnt) ? ((const float4*)(v + (size_t)(node0+n)*128))[c]
                         : make_float4(0.f,0.f,0.f,0.f);
    ((float4*)vl[n])[c] = val;
  }
  __syncthreads();
  const float4* wA = (const float4*)(mA_w + (size_t)t*128);
  const float4* wD = (const float4*)(mD_w + (size_t)t*128);
  float accA[16], accB[16];
#pragma unroll
  for(int n=0;n<16;n++){ accA[n]=0.f; accB[n]=0.f; }
  for(int kc=0;kc<32;kc++){
    float4 wa = wA[kc];
    float4 wd = wD[kc];
#pragma unroll
    for(int n=0;n<16;n++){
      float4 xv = ((const float4*)vl[n])[kc];
      accA[n]=fmaf(wa.x,xv.x,accA[n]); accA[n]=fmaf(wa.y,xv.y,accA[n]);
      accA[n]=fmaf(wa.z,xv.z,accA[n]); accA[n]=fmaf(wa.w,xv.w,accA[n]);
      accB[n]=fmaf(wd.x,xv.x,accB[n]); accB[n]=fmaf(wd.y,xv.y,accB[n]);
      accB[n]=fmaf(wd.z,xv.z,accB[n]); accB[n]=fmaf(wd.w,xv.w,accB[n]);
    }
  }
  float biasA = mA_b[t];
  float wc    = w2[g*512+t];
  for(int n=0;n<16;n++){
    float d = ftanh(accA[n] + biasA) * wc;
    for(int o=32;o>0;o>>=1) d += __shfl_down(d, o);
    if((t&63)==0) red[n][wv] = d;
  }
  __syncthreads();
  if(t<64){
    int n=t>>2, kk=t&3;
    float ae=0.f;
    if(n<cnt){
      // |logit| bounded by sum|mC_w|+|mC_b| (~6): exp safe without max-subtraction
      ae = __expf(red[n][2*kk] + red[n][2*kk+1] + mC_b[kk]);
      atomicAdd(&asum[g*4+kk], ae);
    }
    ael[n][kk]=ae;
  }
  __syncthreads();
  float biasD = mD_b[t];
  float outv = 0.f;
#pragma unroll
  for(int n=0;n<16;n++) outv = fmaf(accB[n]+biasD, ael[n][k], outv);
  atomicAdd(&m2s_num[(size_t)g*512 + t], outv);
}

// ---------------- edge message + scatter-add into nbuf (dst-range filtered) -------
__global__ __launch_bounds__(128,4) void k_edge(const float* __restrict__ v, const float* __restrict__ e,
                       const int* __restrict__ src, const int* __restrict__ dst,
                       const float* K_w, const float* K_b,
                       float* __restrict__ nbuf, int lo, int hi){
  int h = threadIdx.x;             // 0..127
  int e0 = blockIdx.x * 16;
  __shared__ float el[16][16];
  __shared__ int sl[16], dl[16];
  for(int i=h;i<256;i+=128){ int ee=i>>4, c=i&15; el[ee][c]=e[(size_t)(e0+ee)*16+c]; }
  if(h<16){ sl[h]=src[e0+h]; dl[h]=dst[e0+h]; }
  float4 kw[4];
  { const float4* q=(const float4*)(K_w + h*16);
    kw[0]=q[0]; kw[1]=q[1]; kw[2]=q[2]; kw[3]=q[3]; }
  float kb = K_b[h];
  __syncthreads();
  for(int j=0;j<16;j++){
    int dj = dl[j];
    if(dj < lo || dj >= hi) continue;
    int sj = sl[j]; if((u32)sj >= (u32)N_NODES) sj = 0;
    float kv=kb;
#pragma unroll
    for(int i=0;i<4;i++){
      float4 t = kw[i];
      kv = fmaf(t.x, el[j][4*i+0], kv);
      kv = fmaf(t.y, el[j][4*i+1], kv);
      kv = fmaf(t.z, el[j][4*i+2], kv);
      kv = fmaf(t.w, el[j][4*i+3], kv);
    }
    float vs = v[(size_t)sj*128+h];
    float val = kv*vs; val = (val>0.f)? val : 0.1f*val;
    atomicAdd(&nbuf[(size_t)(dj-lo)*128+h], val);
  }
}

// ---------------- fused node pipeline: m2m -> gate -> GRU -> out ------------------
__global__ __launch_bounds__(256,2) void k_node(
    const float* __restrict__ v, const int* __restrict__ graph_id,
    const float* __restrict__ E_w, const float* __restrict__ E_b,
    const float* __restrict__ gmA_w, const float* __restrict__ gmA_b,
    const float* __restrict__ gmB_lin, const float* __restrict__ s2m_g,
    const float* __restrict__ wih, const float* __restrict__ bih,
    const float* __restrict__ whh, const float* __restrict__ bhh,
    const float* __restrict__ nbuf, float* __restrict__ out, int lo){
  int t = threadIdx.x;
  int nl0 = blockIdx.x*16;         // local base in nbuf
  int node0 = lo + nl0;            // global node base
  __shared__ float xl[16][256];    // [0:128]: sve -> m2m -> hgate ; [128:256]: v
  __shared__ float scr[3][16][128];
  __shared__ int gid[16];
  for(int i=t;i<16*32;i+=256){ int n=i>>5,c=i&31;
    ((float4*)xl[n])[c] = ((const float4*)(nbuf + (size_t)(nl0+n)*128))[c]; }
  for(int i=t;i<16*32;i+=256){ int n=i>>5,c=i&31;
    ((float4*)(xl[n]+128))[c] = ((const float4*)(v + (size_t)(node0+n)*128))[c]; }
  if(t<16) gid[t] = graph_id[node0+t] & 63;
  __syncthreads();

  int h = t & 127, kh = t >> 7;

  // ---- phase 1: m2m = leaky(E_w @ [sve; v] + E_b)
  {
    const float4* wE = (const float4*)(E_w + (size_t)h*256 + kh*128);
    float acc[16];
#pragma unroll
    for(int n=0;n<16;n++) acc[n]=0.f;
    for(int kc=0;kc<32;kc++){
      float4 w4 = wE[kc];
#pragma unroll
      for(int n=0;n<16;n++){
        float4 xv = ((const float4*)(xl[n]+kh*128))[kc];
        acc[n]=fmaf(w4.x,xv.x,acc[n]); acc[n]=fmaf(w4.y,xv.y,acc[n]);
        acc[n]=fmaf(w4.z,xv.z,acc[n]); acc[n]=fmaf(w4.w,xv.w,acc[n]);
      }
    }
    __syncthreads();
    if(kh==1){
#pragma unroll
      for(int n=0;n<16;n++) scr[0][n][h]=acc[n];
    }
    __syncthreads();
    if(kh==0){
      float eb = E_b[h];
#pragma unroll
      for(int n=0;n<16;n++){
        float m = acc[n] + scr[0][n][h] + eb;
        m = (m>0.f)? m : 0.1f*m;
        xl[n][h] = m;                       // overwrite sve with m2m
      }
    }
    __syncthreads();
  }

  // ---- phase 2: adaptive gate -> hgate (overwrites m2m in xl[:,0:128])
  {
    const float4* wG = (const float4*)(gmA_w + (size_t)h*128) + kh*16;
    float acc[16];
#pragma unroll
    for(int n=0;n<16;n++) acc[n]=0.f;
    for(int kc=0;kc<16;kc++){
      float4 w4 = wG[kc];
#pragma unroll
      for(int n=0;n<16;n++){
        float4 xv = ((const float4*)xl[n])[kh*16+kc];
        acc[n]=fmaf(w4.x,xv.x,acc[n]); acc[n]=fmaf(w4.y,xv.y,acc[n]);
        acc[n]=fmaf(w4.z,xv.z,acc[n]); acc[n]=fmaf(w4.w,xv.w,acc[n]);
      }
    }
    __syncthreads();
    if(kh==1){
#pragma unroll
      for(int n=0;n<16;n++) scr[0][n][h]=acc[n];
    }
    __syncthreads();
    if(kh==0){
      float ab = gmA_b[h];
#pragma unroll
      for(int n=0;n<16;n++){
        int g = gid[n];
        float z = sigmoidf_(acc[n] + scr[0][n][h] + ab + gmB_lin[g*128+h]);
        float hg = z*s2m_g[g*128+h] + (1.f-z)*xl[n][h];
        xl[n][h] = hg;                      // overwrite m2m with hgate
      }
    }
    __syncthreads();
  }

  // ---- phase 3: GRU  (kh=0: gi = wih @ v ; kh=1: gh = whh @ hgate)
  {
    const float* wbase = (kh==0)? wih : whh;
    int xoff = (kh==0)? 128 : 0;
    const float4* w0 = (const float4*)(wbase + (size_t)h*128);
    const float4* w1 = (const float4*)(wbase + (size_t)(h+128)*128);
    const float4* w2r= (const float4*)(wbase + (size_t)(h+256)*128);
    float a0[16], a1[16], a2[16];
#pragma unroll
    for(int n=0;n<16;n++){ a0[n]=0.f; a1[n]=0.f; a2[n]=0.f; }
    for(int kc=0;kc<32;kc++){
      float4 wv0=w0[kc], wv1=w1[kc], wv2=w2r[kc];
#pragma unroll
      for(int n=0;n<16;n++){
        float4 xv = ((const float4*)(xl[n]+xoff))[kc];
        a0[n]=fmaf(wv0.x,xv.x,a0[n]); a0[n]=fmaf(wv0.y,xv.y,a0[n]);
        a0[n]=fmaf(wv0.z,xv.z,a0[n]); a0[n]=fmaf(wv0.w,xv.w,a0[n]);
        a1[n]=fmaf(wv1.x,xv.x,a1[n]); a1[n]=fmaf(wv1.y,xv.y,a1[n]);
        a1[n]=fmaf(wv1.z,xv.z,a1[n]); a1[n]=fmaf(wv1.w,xv.w,a1[n]);
        a2[n]=fmaf(wv2.x,xv.x,a2[n]); a2[n]=fmaf(wv2.y,xv.y,a2[n]);
        a2[n]=fmaf(wv2.z,xv.z,a2[n]); a2[n]=fmaf(wv2.w,xv.w,a2[n]);
      }
    }
    __syncthreads();
    if(kh==1){
      float b0=bhh[h], b1=bhh[h+128], b2=bhh[h+256];
#pragma unroll
      for(int n=0;n<16;n++){
        scr[0][n][h]=a0[n]+b0; scr[1][n][h]=a1[n]+b1; scr[2][n][h]=a2[n]+b2;
      }
    }
    __syncthreads();
    if(kh==0){
      float b0=bih[h], b1=bih[h+128], b2=bih[h+256];
#pragma unroll
      for(int n=0;n<16;n++){
        float r  = sigmoidf_(a0[n]+b0 + scr[0][n][h]);
        float z  = sigmoidf_(a1[n]+b1 + scr[1][n][h]);
        float nn = ftanh(a2[n]+b2 + r*scr[2][n][h]);
        float hg = xl[n][h];
        out[(size_t)(node0+n)*128+h] = (1.f-z)*nn + z*hg;
      }
    }
  }
}

// ---------------- supernode finish: m2s, gate, GRU -> update_s ---------------------
__global__ __launch_bounds__(128,4) void k_sup2(const float* __restrict__ s,
                       const float* __restrict__ m2s_num, const float* __restrict__ asum,
                       const float* __restrict__ s2s,
                       const float* B_w, const float* B_b,
                       const float* gsA_w, const float* gsA_b,
                       const float* gsB_w, const float* gsB_b,
                       const float* wih, const float* bih, const float* whh, const float* bhh,
                       float* __restrict__ out){
  int b=blockIdx.x, h=threadIdx.x;
  __shared__ float m2si[512], m2sl[128], s2sl[128], sl[128], hgl[128];
  for(int j=0;j<4;j++){ int kh=h+j*128; m2si[kh] = m2s_num[b*512+kh] / asum[b*4 + (kh>>7)]; }
  s2sl[h]=s2s[b*128+h];
  sl[h]=s[b*128+h];
  __syncthreads();
  float acc = B_b[h];
  { const float4* q=(const float4*)(B_w + (size_t)h*512);
#pragma unroll 8
    for(int i=0;i<128;i++){
      float4 p=q[i]; int base=i*4;
      acc=fmaf(p.x,m2si[base+0],acc); acc=fmaf(p.y,m2si[base+1],acc);
      acc=fmaf(p.z,m2si[base+2],acc); acc=fmaf(p.w,m2si[base+3],acc);
    }
  }
  float m2sv = ftanh(acc);
  m2sl[h]=m2sv;
  __syncthreads();
  float zacc = dots(gsA_w+(size_t)h*128, s2sl) + gsA_b[h];
  zacc      += dots(gsB_w+(size_t)h*128, m2sl) + gsB_b[h];
  float z = sigmoidf_(zacc);
  float hg = z*m2sl[h] + (1.f-z)*s2sl[h];
  hgl[h]=hg;
  __syncthreads();
  float gi[3], gh[3];
  for(int j=0;j<3;j++){
    gi[j]=dots(wih+(size_t)(h+j*128)*128, sl)+bih[h+j*128];
    gh[j]=dots(whh+(size_t)(h+j*128)*128, hgl)+bhh[h+j*128];
  }
  float r=sigmoidf_(gi[0]+gh[0]), z2=sigmoidf_(gi[1]+gh[1]);
  float nn=ftanh(gi[2]+r*gh[2]);
  out[(size_t)N_NODES*128 + b*128 + h] = (1.f-z2)*nn + z2*hg;
}

extern "C" void kernel_launch(void* const* d_in, const int* in_sizes, int n_in,
                              void* d_out, int out_size, void* d_ws, size_t ws_size,
                              hipStream_t stream){
  const float* v   = (const float*)d_in[0];
  const float* e   = (const float*)d_in[1];
  const float* s   = (const float*)d_in[2];
  const int* src  = (const int*)d_in[3];
  const int* dst  = (const int*)d_in[4];
  const int* graph_id = (const int*)d_in[5];
  const float* A_w=(const float*)d_in[6];  const float* A_b=(const float*)d_in[7];
  const float* B_w=(const float*)d_in[8];  const float* B_b=(const float*)d_in[9];
  const float* C_w=(const float*)d_in[10]; const float* C_b=(const float*)d_in[11];
  const float* E_w=(const float*)d_in[12]; const float* E_b=(const float*)d_in[13];
  const float* K_w=(const float*)d_in[14]; const float* K_b=(const float*)d_in[15];
  const float* mA_w=(const float*)d_in[16]; const float* mA_b=(const float*)d_in[17];
  const float* mB_w=(const float*)d_in[18]; const float* mB_b=(const float*)d_in[19];
  const float* mC_w=(const float*)d_in[20]; const float* mC_b=(const float*)d_in[21];
  const float* mD_w=(const float*)d_in[22]; const float* mD_b=(const float*)d_in[23];
  const float* gmA_w=(const float*)d_in[24]; const float* gmA_b=(const float*)d_in[25];
  const float* gmB_w=(const float*)d_in[26]; const float* gmB_b=(const float*)d_in[27];
  const float* gm_wih=(const float*)d_in[28]; const float* gm_bih=(const float*)d_in[29];
  const float* gm_whh=(const float*)d_in[30]; const float* gm_bhh=(const float*)d_in[31];
  const float* gsA_w=(const float*)d_in[32]; const float* gsA_b=(const float*)d_in[33];
  const float* gsB_w=(const float*)d_in[34]; const float* gsB_b=(const float*)d_in[35];
  const float* gs_wih=(const float*)d_in[36]; const float* gs_bih=(const float*)d_in[37];
  const float* gs_whh=(const float*)d_in[38]; const float* gs_bhh=(const float*)d_in[39];

  float* ws = (float*)d_ws;
  float* asum    = ws;                  // 256
  float* m2s_num = asum + 256;          // 64*512 = 32768
  float* s2s     = m2s_num + 32768;     // 8192
  float* s2m_g   = s2s + 8192;          // 8192
  float* gmB_lin = s2m_g + 8192;        // 8192
  float* w2      = gmB_lin + 8192;      // 32768
  float* nbuf    = w2 + 32768;          // chunked node buffer
  const size_t small_f = 256 + 32768 + 8192*3 + 32768;   // 90368 floats

  // adaptive node-chunk size from actual ws_size (multiple of 16)
  size_t ws_f = ws_size / 4;
  long avail = (ws_f > small_f) ? (long)(ws_f - small_f) : 0;
  long M = (avail / 128) & ~15L;
  if(M > N_NODES) M = N_NODES;
  if(M < 16) M = 16;

  hipMemsetAsync(asum, 0, (256 + 32768) * sizeof(float), stream);

  k_sup <<<NB, 128, 0, stream>>>(s, A_w,A_b, C_w,C_b, mB_w,mB_b,mC_w, gmB_w,gmB_b,
                                 s2s, s2m_g, w2, gmB_lin);
  k_att <<<NB*CH_PER_G, 512, 0, stream>>>(v, w2, mA_w, mA_b, mC_b, mD_w, mD_b,
                                          asum, m2s_num);
  k_sup2<<<NB, 128, 0, stream>>>(s, m2s_num, asum, s2s, B_w,B_b,
                                 gsA_w,gsA_b, gsB_w,gsB_b,
                                 gs_wih,gs_bih, gs_whh,gs_bhh, (float*)d_out);

  for(long lo = 0; lo < N_NODES; lo += M){
    long cnt = N_NODES - lo; if(cnt > M) cnt = M;       // multiple of 16 (N%16==0)
    int ilo = (int)lo, icnt = (int)cnt;
    hipMemsetAsync(nbuf, 0, (size_t)icnt*128*sizeof(float), stream);
    k_edge<<<N_EDGES/16, 128, 0, stream>>>(v, e, src, dst, K_w, K_b, nbuf, ilo, ilo+icnt);
    k_node<<<icnt/16, 256, 0, stream>>>(v, graph_id, E_w, E_b, gmA_w, gmA_b,
                                        gmB_lin, s2m_g,
                                        gm_wih, gm_bih, gm_whh, gm_bhh,
                                        nbuf, (float*)d_out, ilo);
  }
}

// Round 5
// 2093.939 us; speedup vs baseline: 3.6151x; 1.1242x over previous
//
#include <hip/hip_runtime.h>
#include <math.h>

typedef unsigned int u32;

#define N_NODES 100000
#define N_EDGES 1000000
#define NB      64
#define NODES_PER_G 1562   // N // B; graph 63 holds 1594
#define CH_PER_G 100       // ceil(1594/16)

__device__ __forceinline__ float sigmoidf_(float x){ return 1.f/(1.f+__expf(-x)); }
__device__ __forceinline__ float ftanh(float x){
  float e = __expf(-2.f*fabsf(x));
  float t = (1.f - e)/(1.f + e);
  return copysignf(t, x);
}

// streaming 128-dot: weights from global (L2-hot), x from LDS; no big reg arrays
__device__ __forceinline__ float dots(const float* w, const float* x){
  const float4* w4 = (const float4*)w;
  float a = 0.f;
#pragma unroll 8
  for(int i=0;i<32;i++){
    float4 t = w4[i];
    a = fmaf(t.x, x[4*i+0], a);
    a = fmaf(t.y, x[4*i+1], a);
    a = fmaf(t.z, x[4*i+2], a);
    a = fmaf(t.w, x[4*i+3], a);
  }
  return a;
}

// ---------------- per-graph precompute: s2s, s2m, w2(=dsup*mC), gmB_lin ----------
__global__ __launch_bounds__(128,4) void k_sup(const float* __restrict__ s,
                      const float* A_w, const float* A_b,
                      const float* C_w, const float* C_b,
                      const float* mB_w, const float* mB_b, const float* mC_w,
                      const float* gmB_w, const float* gmB_b,
                      float* s2s, float* s2m_g, float* w2, float* gmB_lin){
  int b = blockIdx.x, h = threadIdx.x;
  __shared__ float sb[128], s2ml[128];
  sb[h] = s[b*128+h];
  __syncthreads();
  s2s[b*128+h] = ftanh(dots(A_w + h*128, sb) + A_b[h]);
  float sm = ftanh(dots(C_w + h*128, sb) + C_b[h]);
  s2m_g[b*128+h] = sm; s2ml[h] = sm;
  for(int k=0;k<4;k++){
    float d = ftanh(dots(mB_w + (size_t)(k*128+h)*128, sb) + mB_b[k*128+h]);
    w2[b*512 + k*128 + h] = d * mC_w[k*128+h];
  }
  __syncthreads();
  gmB_lin[b*128+h] = dots(gmB_w + h*128, s2ml) + gmB_b[h];
}

// ------------- merged attention: mA logits + linearized mD via weighted node-sum --
__global__ __launch_bounds__(512,4) void k_att(const float* __restrict__ v, const float* __restrict__ w2,
                      const float* __restrict__ mA_w, const float* __restrict__ mA_b,
                      const float* __restrict__ mC_b,
                      const float* __restrict__ mD_w, const float* __restrict__ mD_b,
                      float* __restrict__ asum, float* __restrict__ m2s_num){
  int g = blockIdx.x / CH_PER_G, chunk = blockIdx.x % CH_PER_G;
  int start = g*NODES_PER_G, end = (g==NB-1)? N_NODES : start+NODES_PER_G;
  int node0 = start + chunk*16;
  int cnt = end - node0; if(cnt<=0) return; if(cnt>16) cnt=16;
  int t = threadIdx.x; int k = t>>7; int wv = t>>6;
  __shared__ float vl[16][128];
  __shared__ float red[16][8];
  __shared__ float ael[16][4];
  __shared__ float yv[4][128];     // y[k] = sum_n ael[n][k] * v_n
  __shared__ float aes[4];         // sum_n ael[n][k]
  for(int i=t;i<16*32;i+=512){
    int n=i>>5, c=i&31;
    float4 val = (n<cnt) ? ((const float4*)(v + (size_t)(node0+n)*128))[c]
                         : make_float4(0.f,0.f,0.f,0.f);
    ((float4*)vl[n])[c] = val;
  }
  __syncthreads();
  // pass 1: logits for this thread's (k,h) row over 16 nodes
  const float4* wA = (const float4*)(mA_w + (size_t)t*128);
  float accA[16];
#pragma unroll
  for(int n=0;n<16;n++) accA[n]=0.f;
  for(int kc=0;kc<32;kc++){
    float4 wa = wA[kc];
#pragma unroll
    for(int n=0;n<16;n++){
      float4 xv = ((const float4*)vl[n])[kc];
      accA[n]=fmaf(wa.x,xv.x,accA[n]); accA[n]=fmaf(wa.y,xv.y,accA[n]);
      accA[n]=fmaf(wa.z,xv.z,accA[n]); accA[n]=fmaf(wa.w,xv.w,accA[n]);
    }
  }
  float biasA = mA_b[t];
  float wc    = w2[g*512+t];
  for(int n=0;n<16;n++){
    float d = ftanh(accA[n] + biasA) * wc;
    for(int o=32;o>0;o>>=1) d += __shfl_down(d, o);
    if((t&63)==0) red[n][wv] = d;
  }
  __syncthreads();
  if(t<64){
    int n=t>>2, kk=t&3;
    float ae=0.f;
    if(n<cnt){
      // |logit| bounded by sum|mC_w|+|mC_b| (~6): exp safe without max-subtraction
      ae = __expf(red[n][2*kk] + red[n][2*kk+1] + mC_b[kk]);
      atomicAdd(&asum[g*4+kk], ae);
    }
    ael[n][kk]=ae;
  }
  __syncthreads();
  // weighted node-sum y[k][c] (t -> k=t>>7, c=t&127), and sum of weights
  {
    int c = t & 127;
    float y = 0.f;
#pragma unroll
    for(int n=0;n<16;n++) y = fmaf(ael[n][k], vl[n][c], y);
    yv[k][c] = y;
    if(t<4){
      float a0=0.f;
#pragma unroll
      for(int n=0;n<16;n++) a0 += ael[n][t];
      aes[t]=a0;
    }
  }
  __syncthreads();
  // mD matvec once per block on y:  out_t = wD_t . y[k] + biasD_t * sum(ael[:,k])
  float outv = dots(mD_w + (size_t)t*128, yv[k]) + mD_b[t]*aes[k];
  atomicAdd(&m2s_num[(size_t)g*512 + t], outv);
}

// ---------------- edge message + scatter-add into nbuf (dst-range filtered) -------
__global__ __launch_bounds__(128,4) void k_edge(const float* __restrict__ v, const float* __restrict__ e,
                       const int* __restrict__ src, const int* __restrict__ dst,
                       const float* K_w, const float* K_b,
                       float* __restrict__ nbuf, int lo, int hi){
  int h = threadIdx.x;             // 0..127
  int e0 = blockIdx.x * 16;
  __shared__ float el[16][16];
  __shared__ int sl[16], dl[16];
  for(int i=h;i<256;i+=128){ int ee=i>>4, c=i&15; el[ee][c]=e[(size_t)(e0+ee)*16+c]; }
  if(h<16){ sl[h]=src[e0+h]; dl[h]=dst[e0+h]; }
  float4 kw[4];
  { const float4* q=(const float4*)(K_w + h*16);
    kw[0]=q[0]; kw[1]=q[1]; kw[2]=q[2]; kw[3]=q[3]; }
  float kb = K_b[h];
  __syncthreads();
  for(int j=0;j<16;j++){
    int dj = dl[j];
    if(dj < lo || dj >= hi) continue;
    int sj = sl[j]; if((u32)sj >= (u32)N_NODES) sj = 0;
    float kv=kb;
#pragma unroll
    for(int i=0;i<4;i++){
      float4 t = kw[i];
      kv = fmaf(t.x, el[j][4*i+0], kv);
      kv = fmaf(t.y, el[j][4*i+1], kv);
      kv = fmaf(t.z, el[j][4*i+2], kv);
      kv = fmaf(t.w, el[j][4*i+3], kv);
    }
    float vs = v[(size_t)sj*128+h];
    float val = kv*vs; val = (val>0.f)? val : 0.1f*val;
    atomicAdd(&nbuf[(size_t)(dj-lo)*128+h], val);
  }
}

// ---------------- fused node pipeline: m2m -> gate -> GRU -> out ------------------
__global__ __launch_bounds__(256,2) void k_node(
    const float* __restrict__ v, const int* __restrict__ graph_id,
    const float* __restrict__ E_w, const float* __restrict__ E_b,
    const float* __restrict__ gmA_w, const float* __restrict__ gmA_b,
    const float* __restrict__ gmB_lin, const float* __restrict__ s2m_g,
    const float* __restrict__ wih, const float* __restrict__ bih,
    const float* __restrict__ whh, const float* __restrict__ bhh,
    const float* __restrict__ nbuf, float* __restrict__ out, int lo){
  int t = threadIdx.x;
  int nl0 = blockIdx.x*16;         // local base in nbuf
  int node0 = lo + nl0;            // global node base
  __shared__ float xl[16][256];    // [0:128]: sve -> m2m -> hgate ; [128:256]: v
  __shared__ float scr[3][16][128];
  __shared__ int gid[16];
  for(int i=t;i<16*32;i+=256){ int n=i>>5,c=i&31;
    ((float4*)xl[n])[c] = ((const float4*)(nbuf + (size_t)(nl0+n)*128))[c]; }
  for(int i=t;i<16*32;i+=256){ int n=i>>5,c=i&31;
    ((float4*)(xl[n]+128))[c] = ((const float4*)(v + (size_t)(node0+n)*128))[c]; }
  if(t<16) gid[t] = graph_id[node0+t] & 63;
  __syncthreads();

  int h = t & 127, kh = t >> 7;

  // ---- phase 1: m2m = leaky(E_w @ [sve; v] + E_b)
  {
    const float4* wE = (const float4*)(E_w + (size_t)h*256 + kh*128);
    float acc[16];
#pragma unroll
    for(int n=0;n<16;n++) acc[n]=0.f;
    for(int kc=0;kc<32;kc++){
      float4 w4 = wE[kc];
#pragma unroll
      for(int n=0;n<16;n++){
        float4 xv = ((const float4*)(xl[n]+kh*128))[kc];
        acc[n]=fmaf(w4.x,xv.x,acc[n]); acc[n]=fmaf(w4.y,xv.y,acc[n]);
        acc[n]=fmaf(w4.z,xv.z,acc[n]); acc[n]=fmaf(w4.w,xv.w,acc[n]);
      }
    }
    __syncthreads();
    if(kh==1){
#pragma unroll
      for(int n=0;n<16;n++) scr[0][n][h]=acc[n];
    }
    __syncthreads();
    if(kh==0){
      float eb = E_b[h];
#pragma unroll
      for(int n=0;n<16;n++){
        float m = acc[n] + scr[0][n][h] + eb;
        m = (m>0.f)? m : 0.1f*m;
        xl[n][h] = m;                       // overwrite sve with m2m
      }
    }
    __syncthreads();
  }

  // ---- phase 2: adaptive gate -> hgate (overwrites m2m in xl[:,0:128])
  {
    const float4* wG = (const float4*)(gmA_w + (size_t)h*128) + kh*16;
    float acc[16];
#pragma unroll
    for(int n=0;n<16;n++) acc[n]=0.f;
    for(int kc=0;kc<16;kc++){
      float4 w4 = wG[kc];
#pragma unroll
      for(int n=0;n<16;n++){
        float4 xv = ((const float4*)xl[n])[kh*16+kc];
        acc[n]=fmaf(w4.x,xv.x,acc[n]); acc[n]=fmaf(w4.y,xv.y,acc[n]);
        acc[n]=fmaf(w4.z,xv.z,acc[n]); acc[n]=fmaf(w4.w,xv.w,acc[n]);
      }
    }
    __syncthreads();
    if(kh==1){
#pragma unroll
      for(int n=0;n<16;n++) scr[0][n][h]=acc[n];
    }
    __syncthreads();
    if(kh==0){
      float ab = gmA_b[h];
#pragma unroll
      for(int n=0;n<16;n++){
        int g = gid[n];
        float z = sigmoidf_(acc[n] + scr[0][n][h] + ab + gmB_lin[g*128+h]);
        float hg = z*s2m_g[g*128+h] + (1.f-z)*xl[n][h];
        xl[n][h] = hg;                      // overwrite m2m with hgate
      }
    }
    __syncthreads();
  }

  // ---- phase 3: GRU  (kh=0: gi = wih @ v ; kh=1: gh = whh @ hgate)
  {
    const float* wbase = (kh==0)? wih : whh;
    int xoff = (kh==0)? 128 : 0;
    const float4* w0 = (const float4*)(wbase + (size_t)h*128);
    const float4* w1 = (const float4*)(wbase + (size_t)(h+128)*128);
    const float4* w2r= (const float4*)(wbase + (size_t)(h+256)*128);
    float a0[16], a1[16], a2[16];
#pragma unroll
    for(int n=0;n<16;n++){ a0[n]=0.f; a1[n]=0.f; a2[n]=0.f; }
    for(int kc=0;kc<32;kc++){
      float4 wv0=w0[kc], wv1=w1[kc], wv2=w2r[kc];
#pragma unroll
      for(int n=0;n<16;n++){
        float4 xv = ((const float4*)(xl[n]+xoff))[kc];
        a0[n]=fmaf(wv0.x,xv.x,a0[n]); a0[n]=fmaf(wv0.y,xv.y,a0[n]);
        a0[n]=fmaf(wv0.z,xv.z,a0[n]); a0[n]=fmaf(wv0.w,xv.w,a0[n]);
        a1[n]=fmaf(wv1.x,xv.x,a1[n]); a1[n]=fmaf(wv1.y,xv.y,a1[n]);
        a1[n]=fmaf(wv1.z,xv.z,a1[n]); a1[n]=fmaf(wv1.w,xv.w,a1[n]);
        a2[n]=fmaf(wv2.x,xv.x,a2[n]); a2[n]=fmaf(wv2.y,xv.y,a2[n]);
        a2[n]=fmaf(wv2.z,xv.z,a2[n]); a2[n]=fmaf(wv2.w,xv.w,a2[n]);
      }
    }
    __syncthreads();
    if(kh==1){
      float b0=bhh[h], b1=bhh[h+128], b2=bhh[h+256];
#pragma unroll
      for(int n=0;n<16;n++){
        scr[0][n][h]=a0[n]+b0; scr[1][n][h]=a1[n]+b1; scr[2][n][h]=a2[n]+b2;
      }
    }
    __syncthreads();
    if(kh==0){
      float b0=bih[h], b1=bih[h+128], b2=bih[h+256];
#pragma unroll
      for(int n=0;n<16;n++){
        float r  = sigmoidf_(a0[n]+b0 + scr[0][n][h]);
        float z  = sigmoidf_(a1[n]+b1 + scr[1][n][h]);
        float nn = ftanh(a2[n]+b2 + r*scr[2][n][h]);
        float hg = xl[n][h];
        out[(size_t)(node0+n)*128+h] = (1.f-z)*nn + z*hg;
      }
    }
  }
}

// ---------------- supernode finish: m2s, gate, GRU -> update_s ---------------------
__global__ __launch_bounds__(128,4) void k_sup2(const float* __restrict__ s,
                       const float* __restrict__ m2s_num, const float* __restrict__ asum,
                       const float* __restrict__ s2s,
                       const float* B_w, const float* B_b,
                       const float* gsA_w, const float* gsA_b,
                       const float* gsB_w, const float* gsB_b,
                       const float* wih, const float* bih, const float* whh, const float* bhh,
                       float* __restrict__ out){
  int b=blockIdx.x, h=threadIdx.x;
  __shared__ float m2si[512], m2sl[128], s2sl[128], sl[128], hgl[128];
  for(int j=0;j<4;j++){ int kh=h+j*128; m2si[kh] = m2s_num[b*512+kh] / asum[b*4 + (kh>>7)]; }
  s2sl[h]=s2s[b*128+h];
  sl[h]=s[b*128+h];
  __syncthreads();
  float acc = B_b[h];
  { const float4* q=(const float4*)(B_w + (size_t)h*512);
#pragma unroll 8
    for(int i=0;i<128;i++){
      float4 p=q[i]; int base=i*4;
      acc=fmaf(p.x,m2si[base+0],acc); acc=fmaf(p.y,m2si[base+1],acc);
      acc=fmaf(p.z,m2si[base+2],acc); acc=fmaf(p.w,m2si[base+3],acc);
    }
  }
  float m2sv = ftanh(acc);
  m2sl[h]=m2sv;
  __syncthreads();
  float zacc = dots(gsA_w+(size_t)h*128, s2sl) + gsA_b[h];
  zacc      += dots(gsB_w+(size_t)h*128, m2sl) + gsB_b[h];
  float z = sigmoidf_(zacc);
  float hg = z*m2sl[h] + (1.f-z)*s2sl[h];
  hgl[h]=hg;
  __syncthreads();
  float gi[3], gh[3];
  for(int j=0;j<3;j++){
    gi[j]=dots(wih+(size_t)(h+j*128)*128, sl)+bih[h+j*128];
    gh[j]=dots(whh+(size_t)(h+j*128)*128, hgl)+bhh[h+j*128];
  }
  float r=sigmoidf_(gi[0]+gh[0]), z2=sigmoidf_(gi[1]+gh[1]);
  float nn=ftanh(gi[2]+r*gh[2]);
  out[(size_t)N_NODES*128 + b*128 + h] = (1.f-z2)*nn + z2*hg;
}

extern "C" void kernel_launch(void* const* d_in, const int* in_sizes, int n_in,
                              void* d_out, int out_size, void* d_ws, size_t ws_size,
                              hipStream_t stream){
  const float* v   = (const float*)d_in[0];
  const float* e   = (const float*)d_in[1];
  const float* s   = (const float*)d_in[2];
  const int* src  = (const int*)d_in[3];
  const int* dst  = (const int*)d_in[4];
  const int* graph_id = (const int*)d_in[5];
  const float* A_w=(const float*)d_in[6];  const float* A_b=(const float*)d_in[7];
  const float* B_w=(const float*)d_in[8];  const float* B_b=(const float*)d_in[9];
  const float* C_w=(const float*)d_in[10]; const float* C_b=(const float*)d_in[11];
  const float* E_w=(const float*)d_in[12]; const float* E_b=(const float*)d_in[13];
  const float* K_w=(const float*)d_in[14]; const float* K_b=(const float*)d_in[15];
  const float* mA_w=(const float*)d_in[16]; const float* mA_b=(const float*)d_in[17];
  const float* mB_w=(const float*)d_in[18]; const float* mB_b=(const float*)d_in[19];
  const float* mC_w=(const float*)d_in[20]; const float* mC_b=(const float*)d_in[21];
  const float* mD_w=(const float*)d_in[22]; const float* mD_b=(const float*)d_in[23];
  const float* gmA_w=(const float*)d_in[24]; const float* gmA_b=(const float*)d_in[25];
  const float* gmB_w=(const float*)d_in[26]; const float* gmB_b=(const float*)d_in[27];
  const float* gm_wih=(const float*)d_in[28]; const float* gm_bih=(const float*)d_in[29];
  const float* gm_whh=(const float*)d_in[30]; const float* gm_bhh=(const float*)d_in[31];
  const float* gsA_w=(const float*)d_in[32]; const float* gsA_b=(const float*)d_in[33];
  const float* gsB_w=(const float*)d_in[34]; const float* gsB_b=(const float*)d_in[35];
  const float* gs_wih=(const float*)d_in[36]; const float* gs_bih=(const float*)d_in[37];
  const float* gs_whh=(const float*)d_in[38]; const float* gs_bhh=(const float*)d_in[39];

  float* ws = (float*)d_ws;
  float* asum    = ws;                  // 256
  float* m2s_num = asum + 256;          // 64*512 = 32768
  float* s2s     = m2s_num + 32768;     // 8192
  float* s2m_g   = s2s + 8192;          // 8192
  float* gmB_lin = s2m_g + 8192;        // 8192
  float* w2      = gmB_lin + 8192;      // 32768
  float* nbuf    = w2 + 32768;          // chunked node buffer
  const size_t small_f = 256 + 32768 + 8192*3 + 32768;   // 90368 floats

  // adaptive node-chunk size from actual ws_size (multiple of 16)
  size_t ws_f = ws_size / 4;
  long avail = (ws_f > small_f) ? (long)(ws_f - small_f) : 0;
  long M = (avail / 128) & ~15L;
  if(M > N_NODES) M = N_NODES;
  if(M < 16) M = 16;

  hipMemsetAsync(asum, 0, (256 + 32768) * sizeof(float), stream);

  k_sup <<<NB, 128, 0, stream>>>(s, A_w,A_b, C_w,C_b, mB_w,mB_b,mC_w, gmB_w,gmB_b,
                                 s2s, s2m_g, w2, gmB_lin);
  k_att <<<NB*CH_PER_G, 512, 0, stream>>>(v, w2, mA_w, mA_b, mC_b, mD_w, mD_b,
                                          asum, m2s_num);
  k_sup2<<<NB, 128, 0, stream>>>(s, m2s_num, asum, s2s, B_w,B_b,
                                 gsA_w,gsA_b, gsB_w,gsB_b,
                                 gs_wih,gs_bih, gs_whh,gs_bhh, (float*)d_out);

  for(long lo = 0; lo < N_NODES; lo += M){
    long cnt = N_NODES - lo; if(cnt > M) cnt = M;       // multiple of 16 (N%16==0)
    int ilo = (int)lo, icnt = (int)cnt;
    hipMemsetAsync(nbuf, 0, (size_t)icnt*128*sizeof(float), stream);
    k_edge<<<N_EDGES/16, 128, 0, stream>>>(v, e, src, dst, K_w, K_b, nbuf, ilo, ilo+icnt);
    k_node<<<icnt/16, 256, 0, stream>>>(v, graph_id, E_w, E_b, gmA_w, gmA_b,
                                        gmB_lin, s2m_g,
                                        gm_wih, gm_bih, gm_whh, gm_bhh,
                                        nbuf, (float*)d_out, ilo);
  }
}